// Round 8
// baseline (261.293 us; speedup 1.0000x reference)
//
#include <hip/hip_runtime.h>
#include <hip/hip_bf16.h>
#include <math.h>

#define NB   16
#define C1   256
#define C2   256
#define NK   5
#define NEXP (C2 * NK)   // 1280
#define HW   4096

typedef __attribute__((ext_vector_type(8))) short bf16x8;
typedef __attribute__((ext_vector_type(4))) float f32x4;

#define GLOAD_LDS16(g, l) __builtin_amdgcn_global_load_lds( \
    (const __attribute__((address_space(1))) void*)(g), \
    (__attribute__((address_space(3))) void*)(l), 16, 0, 0)

__device__ __forceinline__ unsigned short bfbits(float v) {
    return __builtin_bit_cast(unsigned short, __float2bfloat16(v));
}

// ---------------------------------------------------------------------------
__global__ void weff_kernel(const float* __restrict__ w_path, float* __restrict__ weff) {
    int idx = blockIdx.x * 256 + threadIdx.x;
    if (idx >= NK * C2 * 9) return;
    float s = 0.f;
    #pragma unroll
    for (int p = 0; p < 3; ++p)
        s += w_path[(long)p * NK * C2 * 9 + idx];
    weff[idx] = s;
}

__global__ void cvt_bf16_kernel(const float* __restrict__ in, __hip_bfloat16* __restrict__ out, int n) {
    int i = blockIdx.x * 256 + threadIdx.x;
    if (i < n) out[i] = __float2bfloat16(in[i]);
}

// ---------------------------------------------------------------------------
// MFMA bf16 GEMM, 128x128 tile, BK=32, 4 waves.
// Counted-vmcnt 2-deep pipeline: B(t+2)->regs & A(t+2)->gload_lds issued at
// iter t; ds_write of B(t+1) after MFMA(t); raw s_barrier with
// s_waitcnt vmcnt(18) (this iter's 18 loads stay in flight). A = 3-slot ring.
// ---------------------------------------------------------------------------
template <int NN, int KK, bool FP32B, bool OUT_BF16>
__global__ __launch_bounds__(256)
void gemm_mfma_kernel(const __hip_bfloat16* __restrict__ A,   // [M][KK]
                      const void* __restrict__ B_all,         // [z][KK][NN]
                      void* __restrict__ C_all, int M,
                      long bStrideB, long bStrideC, int bOffB, int bOffC,
                      const float* __restrict__ bn_gamma, const float* __restrict__ bn_beta,
                      const float* __restrict__ bn_mean, const float* __restrict__ bn_var) {
    // 5 x 8KB: As ring slots 0..2 at byte 0/8192/16384, Bs 0..1 at 24576/32768
    __shared__ __align__(16) short LDS[5 * 128 * 32];
    char* const L = (char*)&LDS[0];
    const int z = blockIdx.z;
    const int n0 = blockIdx.x * 128;   // n fastest (L2-friendly, R4-proven)
    const int m0 = blockIdx.y * 128;
    const int t = threadIdx.x;
    const int lane = t & 63;
    const int wid = t >> 6;
    const int wr = wid >> 1, wc = wid & 1;
    const int lr = lane & 15, lg = lane >> 4;

    // ---- A staging (linear dest = t*16 within slot)
    const __hip_bfloat16* aS0 = A + (long)(m0 + (t >> 2)) * KK + (t & 3) * 8;
    const __hip_bfloat16* aS1 = aS0 + (long)64 * KK;

    // ---- B staging: column bn (0..127), k-group kg (0/1)
    const int bn = t & 127;
    const int kg = t >> 7;
    const char* Bbase = (const char*)B_all + (long)(bOffB + z) * bStrideB * (FP32B ? 4 : 2);
    const int bkey = ((bn >> 1) & 3) << 4;
    const int bW0 = bn * 64 + ((kg * 32) ^ bkey);
    const int bW1 = bn * 64 + ((kg * 32 + 16) ^ bkey);

    // ---- fragment read offsets (within a slot)
    int aroff[4], broff[4];
    #pragma unroll
    for (int i = 0; i < 4; ++i) {
        aroff[i] = (wr * 64 + i * 16 + lr) * 64 + lg * 16;
        int n = wc * 64 + i * 16 + lr;
        broff[i] = n * 64 + ((lg * 16) ^ (((n >> 1) & 3) << 4));
    }

    auto loadB = [&](int k0, bf16x8& u0, bf16x8& u1) {
        if constexpr (FP32B) {
            const float* p = (const float*)Bbase + (long)(k0 + kg * 16) * NN + n0 + bn;
            #pragma unroll
            for (int i = 0; i < 8; ++i) u0[i] = (short)bfbits(p[(long)i * NN]);
            #pragma unroll
            for (int i = 0; i < 8; ++i) u1[i] = (short)bfbits(p[(long)(8 + i) * NN]);
        } else {
            const short* p = (const short*)Bbase + (long)(k0 + kg * 16) * NN + n0 + bn;
            #pragma unroll
            for (int i = 0; i < 8; ++i) u0[i] = p[(long)i * NN];
            #pragma unroll
            for (int i = 0; i < 8; ++i) u1[i] = p[(long)(8 + i) * NN];
        }
    };

    f32x4 acc[4][4];
    #pragma unroll
    for (int i = 0; i < 4; ++i)
        #pragma unroll
        for (int j = 0; j < 4; ++j)
            acc[i][j] = (f32x4){0.f, 0.f, 0.f, 0.f};

    constexpr int NT = KK / 32;           // 8
    // ---- prologue: B(0)->e0, A(0)->slot0, A(1)->slot1, B(1)->e1
    bf16x8 e0a, e0b, e1a, e1b;
    loadB(0, e0a, e0b);
    GLOAD_LDS16(aS0,      L + t * 16);
    GLOAD_LDS16(aS1,      L + 4096 + t * 16);
    GLOAD_LDS16(aS0 + 32, L + 8192 + t * 16);
    GLOAD_LDS16(aS1 + 32, L + 8192 + 4096 + t * 16);
    loadB(32, e1a, e1b);
    *(bf16x8*)(L + 24576 + bW0) = e0a;    // ds_write B(0) (compiler waits its loads)
    *(bf16x8*)(L + 24576 + bW1) = e0b;
    asm volatile("s_waitcnt vmcnt(18) lgkmcnt(0)" ::: "memory");  // A(0) landed; A(1)+B(1)=18 fly
    __builtin_amdgcn_sched_barrier(0);
    __builtin_amdgcn_s_barrier();

    #pragma unroll
    for (int it = 0; it < NT; ++it) {
        // issue loads for tile it+2 (B->reg set it&1, A->slot (it+2)%3)
        if (it + 2 < NT) {
            const int k0 = (it + 2) * 32;
            if ((it & 1) == 0) loadB(k0, e0a, e0b); else loadB(k0, e1a, e1b);
            const int as = ((it + 2) % 3) * 8192;
            GLOAD_LDS16(aS0 + k0, L + as + t * 16);
            GLOAD_LDS16(aS1 + k0, L + as + 4096 + t * 16);
        }
        // compute tile it
        const int abase = (it % 3) * 8192;
        const int bbase = 24576 + (it & 1) * 8192;
        bf16x8 af[4], bfr[4];
        #pragma unroll
        for (int i = 0; i < 4; ++i) {
            af[i]  = *(const bf16x8*)(L + abase + aroff[i]);
            bfr[i] = *(const bf16x8*)(L + bbase + broff[i]);
        }
        #pragma unroll
        for (int i = 0; i < 4; ++i)
            #pragma unroll
            for (int j = 0; j < 4; ++j)
                acc[i][j] = __builtin_amdgcn_mfma_f32_16x16x32_bf16(bfr[j], af[i], acc[i][j], 0, 0, 0);
        // ds_write B(it+1) from the set loaded one iter ago (aged -> no stall)
        if (it + 1 < NT) {
            const int wbase = 24576 + ((it + 1) & 1) * 8192;
            if (((it + 1) & 1) == 0) {
                *(bf16x8*)(L + wbase + bW0) = e0a;
                *(bf16x8*)(L + wbase + bW1) = e0b;
            } else {
                *(bf16x8*)(L + wbase + bW0) = e1a;
                *(bf16x8*)(L + wbase + bW1) = e1b;
            }
        }
        // counted barrier: leave this iter's 18 loads in flight; A(it+1) is older -> waited
        if (it < NT - 2) {
            asm volatile("s_waitcnt vmcnt(18) lgkmcnt(0)" ::: "memory");
        } else {
            asm volatile("s_waitcnt vmcnt(0) lgkmcnt(0)" ::: "memory");
        }
        __builtin_amdgcn_sched_barrier(0);
        __builtin_amdgcn_s_barrier();
    }

    // Epilogue (swapped): acc[i][j]: n = n0+wc*64+j*16+lg*4+r, m = m0+wr*64+i*16+lr
    if constexpr (OUT_BF16) {
        __hip_bfloat16* C = (__hip_bfloat16*)C_all + (long)(bOffC + z) * bStrideC;
        #pragma unroll
        for (int i = 0; i < 4; ++i) {
            const int m = m0 + wr * 64 + i * 16 + lr;
            #pragma unroll
            for (int j = 0; j < 4; ++j) {
                const long n = n0 + wc * 64 + j * 16 + lg * 4;
                short4 sv;
                sv.x = (short)bfbits(acc[i][j][0]);
                sv.y = (short)bfbits(acc[i][j][1]);
                sv.z = (short)bfbits(acc[i][j][2]);
                sv.w = (short)bfbits(acc[i][j][3]);
                *(short4*)(C + (long)m * NN + n) = sv;
            }
        }
    } else {
        float* C = (float*)C_all + (long)(bOffC + z) * bStrideC;
        #pragma unroll
        for (int i = 0; i < 4; ++i) {
            const int m = m0 + wr * 64 + i * 16 + lr;
            const float scale = bn_gamma[m] * rsqrtf(bn_var[m] + 1e-5f);
            const float mn = bn_mean[m], bt = bn_beta[m];
            #pragma unroll
            for (int j = 0; j < 4; ++j) {
                const long n = n0 + wc * 64 + j * 16 + lg * 4;
                float4 v;
                float t0 = (acc[i][j][0] - mn) * scale + bt;
                float t1 = (acc[i][j][1] - mn) * scale + bt;
                float t2 = (acc[i][j][2] - mn) * scale + bt;
                float t3 = (acc[i][j][3] - mn) * scale + bt;
                v.x = t0 / (1.0f + __expf(-t0));
                v.y = t1 / (1.0f + __expf(-t1));
                v.z = t2 / (1.0f + __expf(-t2));
                v.w = t3 / (1.0f + __expf(-t3));
                *(float4*)(C + (long)m * NN + n) = v;
            }
        }
    }
}

// ---------------------------------------------------------------------------
// Stage 2: roll + zero-padded depthwise 3x3 + sum over 5 shift groups.
// ---------------------------------------------------------------------------
__global__ __launch_bounds__(256)
void shift_dw_kernel(const __hip_bfloat16* __restrict__ xexp,  // [z][1280][4096]
                     const float* __restrict__ weff,           // [5][256][9]
                     __hip_bfloat16* __restrict__ merged) {    // [z][256][4096]
    __shared__ __align__(16) __hip_bfloat16 sd[NK * 34 * 64];  // 21760 B
    const int t  = threadIdx.x;
    const int r0 = blockIdx.x * 32;        // 0 or 32
    const int c  = blockIdx.y;
    const int z  = blockIdx.z;
    const int shifts[NK] = {-4, -1, 2, 5, 8};
    const __hip_bfloat16* base = xexp + ((long)z * NEXP + (long)c * NK) * HW;

    for (int idx = t; idx < NK * 34 * 8; idx += 256) {
        int k   = idx / (34 * 8);
        int rem = idx - k * (34 * 8);
        int rr  = rem >> 3, ch = (rem & 7) * 8;
        int grow = (r0 - 1 + rr - shifts[k]) & 63;
        *(bf16x8*)&sd[(k * 34 + rr) * 64 + ch] =
            *(const bf16x8*)(base + (long)k * HW + grow * 64 + ch);
    }
    __syncthreads();

    const int j  = t & 63;
    const int ty = t >> 6;                 // 0..3
    const int pbase = ty * 8;
    const bool topEdge = (r0 == 0)  && (ty == 0);
    const bool botEdge = (r0 == 32) && (ty == 3);

    float2 acc[4];
    #pragma unroll
    for (int i = 0; i < 4; ++i) acc[i] = (float2){0.f, 0.f};

    #pragma unroll
    for (int k = 0; k < NK; ++k) {
        const int s = shifts[k];
        const int cL = (j - 1 - s) & 63;
        const int cC = (j - s) & 63;
        const int cR = (j + 1 - s) & 63;
        const float* wp = &weff[((long)k * C2 + c) * 9];
        float w[9];
        #pragma unroll
        for (int i = 0; i < 9; ++i) w[i] = wp[i];
        if (j == 0)  { w[0] = 0.f; w[3] = 0.f; w[6] = 0.f; }
        if (j == 63) { w[2] = 0.f; w[5] = 0.f; w[8] = 0.f; }
        const __hip_bfloat16* pl = &sd[k * 34 * 64];

        float vL[4], vC[4], vR[4];
        #pragma unroll
        for (int w4 = 0; w4 < 4; ++w4) {
            vL[w4] = __bfloat162float(pl[(pbase + w4) * 64 + cL]);
            vC[w4] = __bfloat162float(pl[(pbase + w4) * 64 + cC]);
            vR[w4] = __bfloat162float(pl[(pbase + w4) * 64 + cR]);
        }
        if (topEdge) { vL[0] = 0.f; vC[0] = 0.f; vR[0] = 0.f; }

        #pragma unroll
        for (int pr = 0; pr < 4; ++pr) {
            #pragma unroll
            for (int u = 0; u < 3; ++u) {
                const int wi  = (2 * pr + u) & 3;
                const int wi2 = (2 * pr + u + 1) & 3;
                acc[pr].x += w[u*3+0] * vL[wi]  + w[u*3+1] * vC[wi]  + w[u*3+2] * vR[wi];
                acc[pr].y += w[u*3+0] * vL[wi2] + w[u*3+1] * vC[wi2] + w[u*3+2] * vR[wi2];
            }
            if (pr < 3) {
                const int na = (2 * pr) & 3, nb = (2 * pr + 1) & 3;
                const int ra = pbase + 2 * pr + 4, rb = pbase + 2 * pr + 5;
                vL[na] = __bfloat162float(pl[ra * 64 + cL]);
                vC[na] = __bfloat162float(pl[ra * 64 + cC]);
                vR[na] = __bfloat162float(pl[ra * 64 + cR]);
                vL[nb] = __bfloat162float(pl[rb * 64 + cL]);
                vC[nb] = __bfloat162float(pl[rb * 64 + cC]);
                vR[nb] = __bfloat162float(pl[rb * 64 + cR]);
                if (botEdge && pr == 2) { vL[nb] = 0.f; vC[nb] = 0.f; vR[nb] = 0.f; }
            }
        }
    }

    long outb = ((long)z * C2 + c) * HW + (long)(r0 + ty * 8) * 64 + j;
    #pragma unroll
    for (int pr = 0; pr < 4; ++pr) {
        merged[outb + (long)(2 * pr) * 64]     = __float2bfloat16(acc[pr].x);
        merged[outb + (long)(2 * pr + 1) * 64] = __float2bfloat16(acc[pr].y);
    }
}

// ---------------------------------------------------------------------------
extern "C" void kernel_launch(void* const* d_in, const int* in_sizes, int n_in,
                              void* d_out, int out_size, void* d_ws, size_t ws_size,
                              hipStream_t stream) {
    const float* x        = (const float*)d_in[0];
    const float* w_expand = (const float*)d_in[1];
    const float* w_path   = (const float*)d_in[2];
    const float* w_mix    = (const float*)d_in[3];
    const float* bn_gamma = (const float*)d_in[4];
    const float* bn_beta  = (const float*)d_in[5];
    const float* bn_mean  = (const float*)d_in[6];
    const float* bn_var   = (const float*)d_in[7];

    char* ws = (char*)d_ws;
    float* weff             = (float*)ws;
    __hip_bfloat16* wexp_bf = (__hip_bfloat16*)(ws + 65536);
    __hip_bfloat16* wmix_bf = (__hip_bfloat16*)(ws + 65536 + 655360);
    const size_t head = 1 << 20;

    const size_t xe_per = (size_t)NEXP * HW * 2;   // 10 MB
    const size_t mg_per = (size_t)C2 * HW * 2;     // 2 MB
    const size_t per_b = xe_per + mg_per;          // 12 MB

    int g = 1;
    if (ws_size > head + per_b) {
        size_t fit = (ws_size - head) / per_b;
        g = (int)(fit < NB ? fit : NB);
        if (g < 1) g = 1;
    }

    char* p = ws + head;
    __hip_bfloat16* xexp   = (__hip_bfloat16*)p; p += (size_t)g * xe_per;
    __hip_bfloat16* merged = (__hip_bfloat16*)p;

    weff_kernel<<<(NK * C2 * 9 + 255) / 256, 256, 0, stream>>>(w_path, weff);
    cvt_bf16_kernel<<<(NEXP * C1 + 255) / 256, 256, 0, stream>>>(w_expand, wexp_bf, NEXP * C1);
    cvt_bf16_kernel<<<(C2 * C2 + 255) / 256, 256, 0, stream>>>(w_mix, wmix_bf, C2 * C2);

    for (int b0 = 0; b0 < NB; b0 += g) {
        int gb = (NB - b0) < g ? (NB - b0) : g;
        // expand: A = wexp_bf [1280x256], B = x [z][256][4096] fp32 -> xexp bf16
        gemm_mfma_kernel<HW, C1, true, true><<<dim3(HW / 128, NEXP / 128, gb), 256, 0, stream>>>(
            wexp_bf, x, xexp, NEXP,
            (long)C1 * HW, (long)NEXP * HW, b0, 0,
            nullptr, nullptr, nullptr, nullptr);
        shift_dw_kernel<<<dim3(2, C2, gb), 256, 0, stream>>>(xexp, weff, merged);
        // mix: A = wmix_bf [256x256], B = merged [z][256][4096] bf16 -> d_out fp32
        gemm_mfma_kernel<HW, C2, false, false><<<dim3(HW / 128, C2 / 128, gb), 256, 0, stream>>>(
            wmix_bf, merged, d_out, C2,
            (long)C2 * HW, (long)C2 * HW, 0, b0,
            bn_gamma, bn_beta, bn_mean, bn_var);
    }
}

// Round 9
// 258.294 us; speedup vs baseline: 1.0116x; 1.0116x over previous
//
#include <hip/hip_runtime.h>
#include <hip/hip_bf16.h>
#include <math.h>

#define NB   16
#define C1   256
#define C2   256
#define NK   5
#define NEXP (C2 * NK)   // 1280
#define HW   4096

typedef __attribute__((ext_vector_type(8))) short bf16x8;
typedef __attribute__((ext_vector_type(4))) float f32x4;

__device__ __forceinline__ unsigned short bfbits(float v) {
    return __builtin_bit_cast(unsigned short, __float2bfloat16(v));
}

// ---------------------------------------------------------------------------
__global__ void weff_kernel(const float* __restrict__ w_path, float* __restrict__ weff) {
    int idx = blockIdx.x * 256 + threadIdx.x;
    if (idx >= NK * C2 * 9) return;
    float s = 0.f;
    #pragma unroll
    for (int p = 0; p < 3; ++p)
        s += w_path[(long)p * NK * C2 * 9 + idx];
    weff[idx] = s;
}

__global__ void cvt_bf16_kernel(const float* __restrict__ in, __hip_bfloat16* __restrict__ out, int n) {
    int i = blockIdx.x * 256 + threadIdx.x;
    if (i < n) out[i] = __float2bfloat16(in[i]);
}

// ---------------------------------------------------------------------------
// Weight-stationary MFMA GEMM, K=256 entirely in LDS, ONE barrier per block.
// Block: 512 thr / 8 waves; covers 256 m x 128 n x 256 k.
// - W-frags: 2 strips x 8 ksteps per wave, loaded once from global into VGPRs.
// - x tile: Bs[n=128][k=256] bf16 (64 KB), staged once (fp32->bf16 fused),
//   16B chunks XOR-swizzled by (n&31): writes 2-way (free), reads 4-way.
// - Inner loop: 64 ds_read_b128 + 128 MFMA per wave, no barriers.
// MFMA operands swapped -> D'[n][m], vectorized stores (R5-R8-verified map).
// ---------------------------------------------------------------------------
template <bool FP32B, bool OUT_BF16>
__global__ __launch_bounds__(512, 1)
void ws_gemm_kernel(const __hip_bfloat16* __restrict__ A,   // [M][256] bf16
                    const void* __restrict__ B_all,         // [z][256][4096]
                    void* __restrict__ C_all,
                    long bStrideB, long bStrideC, int bOffB, int bOffC,
                    const float* __restrict__ bn_gamma, const float* __restrict__ bn_beta,
                    const float* __restrict__ bn_mean, const float* __restrict__ bn_var) {
    constexpr int KK = 256, NN = 4096;
    __shared__ __align__(16) char Bs[128 * 512];   // 64 KB
    const int z  = blockIdx.z;
    const int n0 = blockIdx.x * 128;
    const int m0 = blockIdx.y * 256;
    const int t  = threadIdx.x;
    const int lane = t & 63;
    const int wv = t >> 6;            // 0..7
    const int lr = lane & 15, lg = lane >> 4;

    // ---- W fragments, register-resident for the whole kernel
    bf16x8 af[2][8];
    const __hip_bfloat16* wp = A + (long)(m0 + wv * 32 + lr) * KK + lg * 8;
    #pragma unroll
    for (int s = 0; s < 2; ++s)
        #pragma unroll
        for (int ks = 0; ks < 8; ++ks)
            af[s][ks] = *(const bf16x8*)(wp + (long)s * 16 * KK + ks * 32);

    // ---- stage x tile: thread -> (n = t&127, k-section kb = (t>>7)*64)
    const int sn = t & 127;
    const int kb = (t >> 7) * 64;
    const int key = sn & 31;
    const char* Bbase = (const char*)B_all + (long)(bOffB + z) * bStrideB * (FP32B ? 4 : 2);
    #pragma unroll
    for (int gq = 0; gq < 4; ++gq) {               // 16 k's per group
        unsigned u[8];
        if constexpr (FP32B) {
            const float* p = (const float*)Bbase + (long)(kb + gq * 16) * NN + n0 + sn;
            #pragma unroll
            for (int i = 0; i < 8; ++i) {
                float v0 = p[(long)(2 * i) * NN];
                float v1 = p[(long)(2 * i + 1) * NN];
                u[i] = (unsigned)bfbits(v0) | ((unsigned)bfbits(v1) << 16);
            }
        } else {
            const unsigned short* p = (const unsigned short*)Bbase + (long)(kb + gq * 16) * NN + n0 + sn;
            #pragma unroll
            for (int i = 0; i < 8; ++i)
                u[i] = (unsigned)p[(long)(2 * i) * NN] |
                       ((unsigned)p[(long)(2 * i + 1) * NN] << 16);
        }
        const int ch0 = kb / 8 + gq * 2;           // logical 16B chunk index
        *(uint4*)(Bs + sn * 512 + ((ch0 ^ key) * 16))       = *(uint4*)&u[0];
        *(uint4*)(Bs + sn * 512 + (((ch0 + 1) ^ key) * 16)) = *(uint4*)&u[4];
    }
    __syncthreads();                                // the ONLY barrier

    // ---- compute: 8 ksteps x 8 nfrags, each B-frag feeds both m-strips
    f32x4 acc[2][8];
    #pragma unroll
    for (int s = 0; s < 2; ++s)
        #pragma unroll
        for (int j = 0; j < 8; ++j)
            acc[s][j] = (f32x4){0.f, 0.f, 0.f, 0.f};

    #pragma unroll
    for (int ks = 0; ks < 8; ++ks) {
        #pragma unroll
        for (int j = 0; j < 8; ++j) {
            const int n = j * 16 + lr;
            bf16x8 bfr = *(const bf16x8*)(Bs + n * 512 + (((ks * 4 + lg) ^ (n & 31)) * 16));
            acc[0][j] = __builtin_amdgcn_mfma_f32_16x16x32_bf16(bfr, af[0][ks], acc[0][j], 0, 0, 0);
            acc[1][j] = __builtin_amdgcn_mfma_f32_16x16x32_bf16(bfr, af[1][ks], acc[1][j], 0, 0, 0);
        }
    }

    // ---- epilogue: m = m0 + wv*32 + s*16 + lr ; n = n0 + j*16 + lg*4 + r
    if constexpr (OUT_BF16) {
        __hip_bfloat16* C = (__hip_bfloat16*)C_all + (long)(bOffC + z) * bStrideC;
        #pragma unroll
        for (int s = 0; s < 2; ++s) {
            const int m = m0 + wv * 32 + s * 16 + lr;
            #pragma unroll
            for (int j = 0; j < 8; ++j) {
                const long n = n0 + j * 16 + lg * 4;
                short4 sv;
                sv.x = (short)bfbits(acc[s][j][0]);
                sv.y = (short)bfbits(acc[s][j][1]);
                sv.z = (short)bfbits(acc[s][j][2]);
                sv.w = (short)bfbits(acc[s][j][3]);
                *(short4*)(C + (long)m * NN + n) = sv;
            }
        }
    } else {
        float* C = (float*)C_all + (long)(bOffC + z) * bStrideC;
        #pragma unroll
        for (int s = 0; s < 2; ++s) {
            const int m = m0 + wv * 32 + s * 16 + lr;
            const float scale = bn_gamma[m] * rsqrtf(bn_var[m] + 1e-5f);
            const float mn = bn_mean[m], bt = bn_beta[m];
            #pragma unroll
            for (int j = 0; j < 8; ++j) {
                const long n = n0 + j * 16 + lg * 4;
                float4 v;
                float t0 = (acc[s][j][0] - mn) * scale + bt;
                float t1 = (acc[s][j][1] - mn) * scale + bt;
                float t2 = (acc[s][j][2] - mn) * scale + bt;
                float t3 = (acc[s][j][3] - mn) * scale + bt;
                v.x = t0 / (1.0f + __expf(-t0));
                v.y = t1 / (1.0f + __expf(-t1));
                v.z = t2 / (1.0f + __expf(-t2));
                v.w = t3 / (1.0f + __expf(-t3));
                *(float4*)(C + (long)m * NN + n) = v;
            }
        }
    }
}

// ---------------------------------------------------------------------------
// Stage 2: roll + zero-padded depthwise 3x3 + sum over 5 shift groups.
// ---------------------------------------------------------------------------
__global__ __launch_bounds__(256)
void shift_dw_kernel(const __hip_bfloat16* __restrict__ xexp,  // [z][1280][4096]
                     const float* __restrict__ weff,           // [5][256][9]
                     __hip_bfloat16* __restrict__ merged) {    // [z][256][4096]
    __shared__ __align__(16) __hip_bfloat16 sd[NK * 34 * 64];  // 21760 B
    const int t  = threadIdx.x;
    const int r0 = blockIdx.x * 32;        // 0 or 32
    const int c  = blockIdx.y;
    const int z  = blockIdx.z;
    const int shifts[NK] = {-4, -1, 2, 5, 8};
    const __hip_bfloat16* base = xexp + ((long)z * NEXP + (long)c * NK) * HW;

    for (int idx = t; idx < NK * 34 * 8; idx += 256) {
        int k   = idx / (34 * 8);
        int rem = idx - k * (34 * 8);
        int rr  = rem >> 3, ch = (rem & 7) * 8;
        int grow = (r0 - 1 + rr - shifts[k]) & 63;
        *(bf16x8*)&sd[(k * 34 + rr) * 64 + ch] =
            *(const bf16x8*)(base + (long)k * HW + grow * 64 + ch);
    }
    __syncthreads();

    const int j  = t & 63;
    const int ty = t >> 6;                 // 0..3
    const int pbase = ty * 8;
    const bool topEdge = (r0 == 0)  && (ty == 0);
    const bool botEdge = (r0 == 32) && (ty == 3);

    float2 acc[4];
    #pragma unroll
    for (int i = 0; i < 4; ++i) acc[i] = (float2){0.f, 0.f};

    #pragma unroll
    for (int k = 0; k < NK; ++k) {
        const int s = shifts[k];
        const int cL = (j - 1 - s) & 63;
        const int cC = (j - s) & 63;
        const int cR = (j + 1 - s) & 63;
        const float* wp = &weff[((long)k * C2 + c) * 9];
        float w[9];
        #pragma unroll
        for (int i = 0; i < 9; ++i) w[i] = wp[i];
        if (j == 0)  { w[0] = 0.f; w[3] = 0.f; w[6] = 0.f; }
        if (j == 63) { w[2] = 0.f; w[5] = 0.f; w[8] = 0.f; }
        const __hip_bfloat16* pl = &sd[k * 34 * 64];

        float vL[4], vC[4], vR[4];
        #pragma unroll
        for (int w4 = 0; w4 < 4; ++w4) {
            vL[w4] = __bfloat162float(pl[(pbase + w4) * 64 + cL]);
            vC[w4] = __bfloat162float(pl[(pbase + w4) * 64 + cC]);
            vR[w4] = __bfloat162float(pl[(pbase + w4) * 64 + cR]);
        }
        if (topEdge) { vL[0] = 0.f; vC[0] = 0.f; vR[0] = 0.f; }

        #pragma unroll
        for (int pr = 0; pr < 4; ++pr) {
            #pragma unroll
            for (int u = 0; u < 3; ++u) {
                const int wi  = (2 * pr + u) & 3;
                const int wi2 = (2 * pr + u + 1) & 3;
                acc[pr].x += w[u*3+0] * vL[wi]  + w[u*3+1] * vC[wi]  + w[u*3+2] * vR[wi];
                acc[pr].y += w[u*3+0] * vL[wi2] + w[u*3+1] * vC[wi2] + w[u*3+2] * vR[wi2];
            }
            if (pr < 3) {
                const int na = (2 * pr) & 3, nb = (2 * pr + 1) & 3;
                const int ra = pbase + 2 * pr + 4, rb = pbase + 2 * pr + 5;
                vL[na] = __bfloat162float(pl[ra * 64 + cL]);
                vC[na] = __bfloat162float(pl[ra * 64 + cC]);
                vR[na] = __bfloat162float(pl[ra * 64 + cR]);
                vL[nb] = __bfloat162float(pl[rb * 64 + cL]);
                vC[nb] = __bfloat162float(pl[rb * 64 + cC]);
                vR[nb] = __bfloat162float(pl[rb * 64 + cR]);
                if (botEdge && pr == 2) { vL[nb] = 0.f; vC[nb] = 0.f; vR[nb] = 0.f; }
            }
        }
    }

    long outb = ((long)z * C2 + c) * HW + (long)(r0 + ty * 8) * 64 + j;
    #pragma unroll
    for (int pr = 0; pr < 4; ++pr) {
        merged[outb + (long)(2 * pr) * 64]     = __float2bfloat16(acc[pr].x);
        merged[outb + (long)(2 * pr + 1) * 64] = __float2bfloat16(acc[pr].y);
    }
}

// ---------------------------------------------------------------------------
extern "C" void kernel_launch(void* const* d_in, const int* in_sizes, int n_in,
                              void* d_out, int out_size, void* d_ws, size_t ws_size,
                              hipStream_t stream) {
    const float* x        = (const float*)d_in[0];
    const float* w_expand = (const float*)d_in[1];
    const float* w_path   = (const float*)d_in[2];
    const float* w_mix    = (const float*)d_in[3];
    const float* bn_gamma = (const float*)d_in[4];
    const float* bn_beta  = (const float*)d_in[5];
    const float* bn_mean  = (const float*)d_in[6];
    const float* bn_var   = (const float*)d_in[7];

    char* ws = (char*)d_ws;
    float* weff             = (float*)ws;
    __hip_bfloat16* wexp_bf = (__hip_bfloat16*)(ws + 65536);
    __hip_bfloat16* wmix_bf = (__hip_bfloat16*)(ws + 65536 + 655360);
    const size_t head = 1 << 20;

    const size_t xe_per = (size_t)NEXP * HW * 2;   // 10 MB
    const size_t mg_per = (size_t)C2 * HW * 2;     // 2 MB
    const size_t per_b = xe_per + mg_per;          // 12 MB

    int g = 1;
    if (ws_size > head + per_b) {
        size_t fit = (ws_size - head) / per_b;
        g = (int)(fit < NB ? fit : NB);
        if (g < 1) g = 1;
    }

    char* p = ws + head;
    __hip_bfloat16* xexp   = (__hip_bfloat16*)p; p += (size_t)g * xe_per;
    __hip_bfloat16* merged = (__hip_bfloat16*)p;

    weff_kernel<<<(NK * C2 * 9 + 255) / 256, 256, 0, stream>>>(w_path, weff);
    cvt_bf16_kernel<<<(NEXP * C1 + 255) / 256, 256, 0, stream>>>(w_expand, wexp_bf, NEXP * C1);
    cvt_bf16_kernel<<<(C2 * C2 + 255) / 256, 256, 0, stream>>>(w_mix, wmix_bf, C2 * C2);

    for (int b0 = 0; b0 < NB; b0 += g) {
        int gb = (NB - b0) < g ? (NB - b0) : g;
        // expand: A = wexp_bf [1280x256], B = x [z][256][4096] fp32 -> xexp bf16
        ws_gemm_kernel<true, true><<<dim3(HW / 128, NEXP / 256, gb), 512, 0, stream>>>(
            wexp_bf, x, xexp,
            (long)C1 * HW, (long)NEXP * HW, b0, 0,
            nullptr, nullptr, nullptr, nullptr);
        shift_dw_kernel<<<dim3(2, C2, gb), 256, 0, stream>>>(xexp, weff, merged);
        // mix: A = wmix_bf [256x256], B = merged [z][256][4096] bf16 -> d_out fp32
        ws_gemm_kernel<false, false><<<dim3(HW / 128, 1, gb), 512, 0, stream>>>(
            wmix_bf, merged, d_out,
            (long)C2 * HW, (long)C2 * HW, 0, b0,
            bn_gamma, bn_beta, bn_mean, bn_var);
    }
}